// Round 1
// baseline (913.498 us; speedup 1.0000x reference)
//
#include <hip/hip_runtime.h>
#include <math.h>

// MoE conv container: out[b] = sum_e wcomb[e,b] * SiLU(BN_e(Conv3x3_e(x[b])))
// B=64, C=32, H=W=128, E=4, K=2. fp32 throughout (round 1: correctness-first).
//
// Design: block = (sample, 16x16 spatial tile), 256 threads = 1 thread/pixel,
// all 32 output channels accumulated in registers. Input tile staged in LDS
// (32ci x 18x18 halo, row stride 19). Weights read as wave-uniform scalar
// loads (e/ci/co all uniform) so the VALU pipe stays pure FMA.

#define B_ 64
#define C_ 32
#define H_ 128
#define W_ 128
#define E_ 4
#define K_ 2
#define EPS_ 1e-5f

#define TH 16
#define TW 16
#define HALO_H (TH + 2)   // 18
#define HALO_W (TW + 2)   // 18
#define SSTRIDE 19        // odd stride to spread LDS banks

__global__ __launch_bounds__(256, 3)
void moe_conv_bn_silu_kernel(const float* __restrict__ x,
                             const float* __restrict__ weights,
                             const int* __restrict__ indices,
                             const float* __restrict__ Wc,
                             const float* __restrict__ gamma,
                             const float* __restrict__ beta,
                             const float* __restrict__ mean,
                             const float* __restrict__ var,
                             float* __restrict__ out) {
  __shared__ float smem[C_ * HALO_H * SSTRIDE];  // 32*18*19*4 = 43,776 B

  const int tid = threadIdx.x;
  const int tiles_per_row = W_ / TW;              // 8
  const int tiles_per_img = (H_ / TH) * tiles_per_row;  // 64
  const int b    = blockIdx.x / tiles_per_img;
  const int tile = blockIdx.x % tiles_per_img;
  const int th0 = (tile / tiles_per_row) * TH;
  const int tw0 = (tile % tiles_per_row) * TW;

  // Combined routing weight per expert for this sample (identical across threads).
  float wcomb[E_];
#pragma unroll
  for (int e = 0; e < E_; ++e) wcomb[e] = 0.f;
#pragma unroll
  for (int k = 0; k < K_; ++k) {
    int   ek = indices[b * K_ + k];
    float wk = weights[b * K_ + k];
#pragma unroll
    for (int e = 0; e < E_; ++e) wcomb[e] += (ek == e) ? wk : 0.f;
  }

  // Stage input tile with halo (zero-padded at image borders) into LDS.
  const float* xb = x + (size_t)b * C_ * H_ * W_;
  const int total = C_ * HALO_H * HALO_W;  // 10368
  for (int i = tid; i < total; i += 256) {
    int ci   = i / (HALO_H * HALO_W);
    int rem  = i % (HALO_H * HALO_W);
    int r    = rem / HALO_W;
    int ccol = rem % HALO_W;
    int gh = th0 + r - 1;
    int gw = tw0 + ccol - 1;
    float v = 0.f;
    if (gh >= 0 && gh < H_ && gw >= 0 && gw < W_)
      v = xb[(size_t)ci * H_ * W_ + (size_t)gh * W_ + gw];
    smem[ci * (HALO_H * SSTRIDE) + r * SSTRIDE + ccol] = v;
  }
  __syncthreads();

  const int ty = tid / TW;
  const int tx = tid % TW;

  float out_acc[C_];
#pragma unroll
  for (int co = 0; co < C_; ++co) out_acc[co] = 0.f;

  for (int e = 0; e < E_; ++e) {
    float wce = wcomb[e];
    // Uniform skip of non-routed experts (wcomb identical across lanes).
    int skip = (wce == 0.f) ? 1 : 0;
    skip = __builtin_amdgcn_readfirstlane(skip);
    if (skip) continue;

    float acc[C_];
#pragma unroll
    for (int co = 0; co < C_; ++co) acc[co] = 0.f;

    const float* wbase = Wc + (size_t)e * C_ * C_ * 9;

    for (int ci = 0; ci < C_; ++ci) {
      const float* srow = &smem[ci * (HALO_H * SSTRIDE)];
      float in[9];
#pragma unroll
      for (int dy = 0; dy < 3; ++dy)
#pragma unroll
        for (int dx = 0; dx < 3; ++dx)
          in[dy * 3 + dx] = srow[(ty + dy) * SSTRIDE + (tx + dx)];

      const float* wci = wbase + ci * 9;  // Wc[e][co][ci][0..8], stride C_*9 per co
#pragma unroll
      for (int co = 0; co < C_; ++co) {
        const float* wp = wci + (size_t)co * C_ * 9;  // wave-uniform -> s_load
        float a = acc[co];
        a = fmaf(in[0], wp[0], a);
        a = fmaf(in[1], wp[1], a);
        a = fmaf(in[2], wp[2], a);
        a = fmaf(in[3], wp[3], a);
        a = fmaf(in[4], wp[4], a);
        a = fmaf(in[5], wp[5], a);
        a = fmaf(in[6], wp[6], a);
        a = fmaf(in[7], wp[7], a);
        a = fmaf(in[8], wp[8], a);
        acc[co] = a;
      }
    }

    // BN (inference stats) + SiLU + routed-weight accumulate.
#pragma unroll
    for (int co = 0; co < C_; ++co) {
      float g  = gamma[e * C_ + co];
      float bt = beta[e * C_ + co];
      float m  = mean[e * C_ + co];
      float v  = var[e * C_ + co];
      float sc = g * rsqrtf(v + EPS_);
      float y  = acc[co] * sc + (bt - m * sc);
      float s  = 1.f / (1.f + __expf(-y));
      out_acc[co] += wce * y * s;
    }
  }

  // Write out: threads cover 16 consecutive columns -> 64B-contiguous chunks.
  float* ob = out + (size_t)b * C_ * H_ * W_ + (size_t)(th0 + ty) * W_ + (tw0 + tx);
#pragma unroll
  for (int co = 0; co < C_; ++co)
    ob[(size_t)co * H_ * W_] = out_acc[co];
}

extern "C" void kernel_launch(void* const* d_in, const int* in_sizes, int n_in,
                              void* d_out, int out_size, void* d_ws, size_t ws_size,
                              hipStream_t stream) {
  const float* x       = (const float*)d_in[0];
  const float* weights = (const float*)d_in[1];
  const int*   indices = (const int*)d_in[2];
  const float* Wc      = (const float*)d_in[3];
  const float* gamma   = (const float*)d_in[4];
  const float* beta    = (const float*)d_in[5];
  const float* mean    = (const float*)d_in[6];
  const float* var     = (const float*)d_in[7];
  float* out = (float*)d_out;

  const int tiles_per_img = (H_ / TH) * (W_ / TW);  // 64
  dim3 grid(B_ * tiles_per_img);                    // 4096 blocks
  dim3 block(256);
  moe_conv_bn_silu_kernel<<<grid, block, 0, stream>>>(
      x, weights, indices, Wc, gamma, beta, mean, var, out);
}

// Round 2
// 129.772 us; speedup vs baseline: 7.0393x; 7.0393x over previous
//
#include <hip/hip_runtime.h>
#include <math.h>

// MoE conv container via bf16 MFMA implicit GEMM.
// out[b] = sum_k weights[b,k] * SiLU(BN_{idx[b,k]}(Conv3x3_{idx[b,k]}(x[b])))
// B=64, C=32, H=W=128, E=4, K=2.
//
// Block = (sample, 16x16 pixel tile), 256 threads = 4 waves.
// GEMM view: out[co=32, pix] = A[co, k=288] x Bmat[k, pix], k = o*32+ci (o=3x3 tap).
//  - input halo tile 18x18 staged channel-last bf16 (64B/pixel), XOR-swizzled
//    16B slots -> stride-64 ds_read_b128 B-frags are <=2-way conflicts (free).
//  - weights transposed to A[co][o*32+ci] bf16, row stride 592B (37*16B, odd ->
//    conflict-free A-frag ds_read_b128).
//  - mfma_f32_16x16x32_bf16; wave w owns pixel rows 4w..4w+3, all 32 co.
//    acc[slot 2][mtile 2][row 4] fp32x4 = 64 VGPR. B-frags shared across slots.
//  - block-uniform fold when both top-k slots hit the same expert.

#define B_ 64
#define C_ 32
#define H_ 128
#define W_ 128
#define E_ 4
#define K_ 2
#define EPS_ 1e-5f
#define HW_ (H_ * W_)

#define TH 16
#define TW 16
#define HALO 18
#define NPX (HALO * HALO)          // 324 halo pixels
#define PX_B 64                    // 32 ci * 2B channel-last
#define AROW_B 592                 // 288 bf16 = 576B + 16B pad (odd 16B stride)
#define IN_LDS_B (NPX * PX_B)      // 20736
#define A_LDS_B (C_ * AROW_B)      // 18944
#define SC_OFF (IN_LDS_B + 2 * A_LDS_B)   // 58624
#define LDS_TOTAL (SC_OFF + 2 * C_ * 8)   // + scale/shift: 59136

typedef __attribute__((ext_vector_type(4))) float  f32x4;
typedef __attribute__((ext_vector_type(8))) short  bf16x8;
typedef __attribute__((ext_vector_type(8))) unsigned short u16x8;
typedef __attribute__((ext_vector_type(4))) unsigned short u16x4;

__device__ inline unsigned short f2bf(float f) {  // round-to-nearest-even
  unsigned u = __builtin_bit_cast(unsigned, f);
  return (unsigned short)((u + 0x7fffu + ((u >> 16) & 1u)) >> 16);
}

__global__ __launch_bounds__(256, 2)
void moe_mfma_kernel(const float* __restrict__ x,
                     const float* __restrict__ weights,
                     const int* __restrict__ indices,
                     const float* __restrict__ Wc,
                     const float* __restrict__ gamma,
                     const float* __restrict__ beta,
                     const float* __restrict__ mean,
                     const float* __restrict__ var,
                     float* __restrict__ out) {
  __shared__ __align__(16) unsigned char lds[LDS_TOTAL];
  unsigned char* in_t = lds;
  unsigned char* aw0  = lds + IN_LDS_B;
  unsigned char* aw1  = lds + IN_LDS_B + A_LDS_B;
  float*         scsh = (float*)(lds + SC_OFF);   // [slot][co][2] = scale, shift

  const int tid  = threadIdx.x;
  const int tiles_per_row = W_ / TW;                    // 8
  const int tiles_per_img = (H_ / TH) * tiles_per_row;  // 64
  const int b    = blockIdx.x / tiles_per_img;
  const int tile = blockIdx.x % tiles_per_img;
  const int th0  = (tile / tiles_per_row) * TH;
  const int tw0  = (tile % tiles_per_row) * TW;

  const int   e0  = indices[b * K_ + 0];
  const int   e1  = indices[b * K_ + 1];
  const float wk0 = weights[b * K_ + 0];
  const float wk1 = weights[b * K_ + 1];
  const bool  dup = (e0 == e1);          // block-uniform
  const float wka = dup ? (wk0 + wk1) : wk0;

  // ---- stage input halo tile: channel-last bf16, swizzled 16B slots ----
  const float* xb = x + (size_t)b * C_ * HW_;
  for (int i = tid; i < NPX * 4; i += 256) {
    int px = i % NPX;          // halo pixel (consecutive tids -> consecutive px)
    int cb = i / NPX;          // ci block of 8
    int hy = px / HALO, hx = px % HALO;
    int gh = th0 + hy - 1, gw = tw0 + hx - 1;
    u16x8 pk = (u16x8)0;
    if (gh >= 0 && gh < H_ && gw >= 0 && gw < W_) {
      const float* src = xb + (size_t)(cb * 8) * HW_ + (size_t)gh * W_ + gw;
#pragma unroll
      for (int j = 0; j < 8; ++j) pk[j] = f2bf(src[(size_t)j * HW_]);
    }
    int slot = cb ^ (px & 3);
    *(u16x8*)(in_t + px * PX_B + slot * 16) = pk;
  }

  // ---- stage per-slot weights: A[co][o*32+ci] bf16, row stride 592B ----
  {
    int co  = tid >> 3;            // 0..31
    int ci4 = (tid & 7) * 4;       // 0,4,..,28
#pragma unroll
    for (int s = 0; s < 2; ++s) {
      int e = s ? e1 : e0;
      const float* wp = Wc + (size_t)e * C_ * C_ * 9 + (size_t)co * C_ * 9 + (size_t)ci4 * 9;
      float wv[36];
#pragma unroll
      for (int j = 0; j < 36; ++j) wv[j] = wp[j];   // Wc[e][co][ci4..+3][0..8]
      unsigned char* arow = (s ? aw1 : aw0) + co * AROW_B + ci4 * 2;
#pragma unroll
      for (int o = 0; o < 9; ++o) {
        u16x4 pk;
#pragma unroll
        for (int q = 0; q < 4; ++q) pk[q] = f2bf(wv[q * 9 + o]);
        *(u16x4*)(arow + o * 64) = pk;
      }
    }
  }

  // ---- BN scale/shift per (slot, co) ----
  if (tid < 64) {
    int s  = tid >> 5;
    int co = tid & 31;
    int e  = s ? e1 : e0;
    float g  = gamma[e * C_ + co];
    float bt = beta[e * C_ + co];
    float mn = mean[e * C_ + co];
    float vr = var[e * C_ + co];
    float sc = g * rsqrtf(vr + EPS_);
    scsh[(s * C_ + co) * 2 + 0] = sc;
    scsh[(s * C_ + co) * 2 + 1] = bt - mn * sc;
  }
  __syncthreads();

  const int lane = tid & 63;
  const int w    = tid >> 6;      // wave 0..3 -> pixel rows 4w..4w+3
  const int lx   = lane & 15;     // pixel col / A row (co) within M-tile
  const int sl   = lane >> 4;     // k-slot

  f32x4 acc[2][2][4];             // [slot][mtile][row j]
#pragma unroll
  for (int s = 0; s < 2; ++s)
#pragma unroll
    for (int m = 0; m < 2; ++m)
#pragma unroll
      for (int j = 0; j < 4; ++j) acc[s][m][j] = (f32x4){0.f, 0.f, 0.f, 0.f};

  int dy = 0, dx = 0;
#pragma unroll 1
  for (int o = 0; o < 9; ++o) {
    bf16x8 bf[4];
#pragma unroll
    for (int j = 0; j < 4; ++j) {
      int hp   = (4 * w + j + dy) * HALO + (lx + dx);
      int slot = sl ^ (hp & 3);
      bf[j] = *(const bf16x8*)(in_t + hp * PX_B + slot * 16);
    }
    bf16x8 af0[2], af1[2];
#pragma unroll
    for (int m = 0; m < 2; ++m) {
      int ro = (m * 16 + lx) * AROW_B + o * 64 + sl * 16;
      af0[m] = *(const bf16x8*)(aw0 + ro);
      af1[m] = *(const bf16x8*)(aw1 + ro);
    }
#pragma unroll
    for (int m = 0; m < 2; ++m)
#pragma unroll
      for (int j = 0; j < 4; ++j)
        acc[0][m][j] = __builtin_amdgcn_mfma_f32_16x16x32_bf16(af0[m], bf[j], acc[0][m][j], 0, 0, 0);
    if (!dup) {
#pragma unroll
      for (int m = 0; m < 2; ++m)
#pragma unroll
        for (int j = 0; j < 4; ++j)
          acc[1][m][j] = __builtin_amdgcn_mfma_f32_16x16x32_bf16(af1[m], bf[j], acc[1][m][j], 0, 0, 0);
    }
    if (++dx == 3) { dx = 0; ++dy; }
  }

  // ---- epilogue: BN + SiLU + routed-weight combine ----
  float res[2][4][4];             // [mtile][row j][reg r]
#pragma unroll
  for (int m = 0; m < 2; ++m)
#pragma unroll
    for (int j = 0; j < 4; ++j)
#pragma unroll
      for (int r = 0; r < 4; ++r) res[m][j][r] = 0.f;

#pragma unroll
  for (int s = 0; s < 2; ++s) {
    if (s == 1 && dup) break;
    float wk = s ? wk1 : wka;
#pragma unroll
    for (int m = 0; m < 2; ++m)
#pragma unroll
      for (int r = 0; r < 4; ++r) {
        int co = m * 16 + sl * 4 + r;
        float sc = scsh[(s * C_ + co) * 2 + 0];
        float sh = scsh[(s * C_ + co) * 2 + 1];
#pragma unroll
        for (int j = 0; j < 4; ++j) {
          float y = acc[s][m][j][r] * sc + sh;
          float sig = 1.f / (1.f + __expf(-y));
          res[m][j][r] += wk * y * sig;
        }
      }
  }

  // ---- store: lanes 0..15 cover 16 consecutive columns ----
#pragma unroll
  for (int m = 0; m < 2; ++m)
#pragma unroll
    for (int r = 0; r < 4; ++r) {
      int co = m * 16 + sl * 4 + r;
      float* ob = out + ((size_t)b * C_ + co) * HW_ + (size_t)(th0) * W_ + tw0 + lx;
#pragma unroll
      for (int j = 0; j < 4; ++j)
        ob[(size_t)(4 * w + j) * W_] = res[m][j][r];
    }
}

extern "C" void kernel_launch(void* const* d_in, const int* in_sizes, int n_in,
                              void* d_out, int out_size, void* d_ws, size_t ws_size,
                              hipStream_t stream) {
  const float* x       = (const float*)d_in[0];
  const float* weights = (const float*)d_in[1];
  const int*   indices = (const int*)d_in[2];
  const float* Wc      = (const float*)d_in[3];
  const float* gamma   = (const float*)d_in[4];
  const float* beta    = (const float*)d_in[5];
  const float* mean    = (const float*)d_in[6];
  const float* var     = (const float*)d_in[7];
  float* out = (float*)d_out;

  dim3 grid(B_ * (H_ / TH) * (W_ / TW));  // 4096
  dim3 block(256);
  moe_mfma_kernel<<<grid, block, 0, stream>>>(
      x, weights, indices, Wc, gamma, beta, mean, var, out);
}

// Round 3
// 118.974 us; speedup vs baseline: 7.6781x; 1.0908x over previous
//
#include <hip/hip_runtime.h>
#include <math.h>

// MoE conv container, two-phase:
//  prep: x NCHW fp32 -> zero-padded NHWC bf16 (130x130x32) in ws, + weights ->
//        MFMA A-layout bf16 + BN scale/shift tables.
//  conv: per (sample, 4 horizontal 16x16 tiles): A + input staged via
//        global_load_lds (16B), input double-buffered (issue-before-compute),
//        mfma_f32_16x16x32_bf16, BN+SiLU+routed-combine epilogue.
// Fallback to single-kernel (R2) path if ws too small.

#define B_ 64
#define C_ 32
#define H_ 128
#define W_ 128
#define E_ 4
#define K_ 2
#define EPS_ 1e-5f
#define HW_ (H_ * W_)
#define HP_ 130
#define WP_ 130

#define AROW_B 592                          // 288 bf16 + 16B pad (odd 16B stride)
#define A_LDS_B (C_ * AROW_B)               // 18944 per expert
#define XPAD_BYTES ((size_t)B_ * HP_ * WP_ * C_ * 2)   // 69,222,400
#define AW_OFF   XPAD_BYTES
#define AW_BYTES ((size_t)E_ * A_LDS_B)     // 75,776
#define SCSH_OFF (AW_OFF + AW_BYTES)
#define WS_NEEDED (SCSH_OFF + (size_t)E_ * C_ * 2 * 4)

#define TH 16
#define TW 16
#define HALO 18
#define NPX (HALO * HALO)          // 324
#define NCHUNK (NPX * 4)           // 1296 16B chunks per input tile
#define BUF_B (NCHUNK * 16)        // 20736

// conv LDS layout
#define LDS_AW   0
#define LDS_BUF0 (2 * A_LDS_B)             // 37888
#define LDS_BUF1 (LDS_BUF0 + BUF_B)        // 58624
#define LDS_SCSH (LDS_BUF1 + BUF_B)        // 79360
#define LDS_TOT  (LDS_SCSH + 512)          // 79872  (2 blocks/CU)

typedef __attribute__((ext_vector_type(4))) float  f32x4;
typedef __attribute__((ext_vector_type(8))) short  bf16x8;
typedef __attribute__((ext_vector_type(8))) unsigned short u16x8;
typedef __attribute__((ext_vector_type(4))) unsigned short u16x4;

__device__ inline unsigned short f2bf(float f) {  // round-to-nearest-even
  unsigned u = __builtin_bit_cast(unsigned, f);
  return (unsigned short)((u + 0x7fffu + ((u >> 16) & 1u)) >> 16);
}

__device__ inline void gload16(const void* g, const void* l) {
  __builtin_amdgcn_global_load_lds(
      (const __attribute__((address_space(1))) unsigned int*)g,
      (__attribute__((address_space(3))) unsigned int*)l, 16, 0, 0);
}

// ---------------- phase A: transpose/convert + weight prep ----------------
__global__ __launch_bounds__(256, 4)
void prep_kernel(const float* __restrict__ x,
                 const float* __restrict__ Wc,
                 const float* __restrict__ gamma,
                 const float* __restrict__ beta,
                 const float* __restrict__ mean,
                 const float* __restrict__ var,
                 unsigned short* __restrict__ wsu) {
  const int bid = blockIdx.x;
  const int tid = threadIdx.x;

  if (bid >= B_ * HP_) {
    // ---- weight block: expert e -> A[e][co][o*32+ci] bf16, stride 592B ----
    int e = bid - B_ * HP_;
    unsigned short* aw = (unsigned short*)((char*)wsu + AW_OFF) + (size_t)e * (A_LDS_B / 2);
    int co  = tid >> 3;
    int ci4 = (tid & 7) * 4;
    const float* wp = Wc + (((size_t)e * C_ + co) * C_ + ci4) * 9;
    float wv[36];
#pragma unroll
    for (int j = 0; j < 36; ++j) wv[j] = wp[j];
    unsigned short* arow = aw + co * (AROW_B / 2) + ci4;
#pragma unroll
    for (int o = 0; o < 9; ++o) {
      u16x4 pk;
#pragma unroll
      for (int q = 0; q < 4; ++q) pk[q] = f2bf(wv[q * 9 + o]);
      *(u16x4*)(arow + o * C_) = pk;
    }
    if (tid < C_) {
      float g  = gamma[e * C_ + tid];
      float bt = beta[e * C_ + tid];
      float mn = mean[e * C_ + tid];
      float vr = var[e * C_ + tid];
      float sc = g * rsqrtf(vr + EPS_);
      float* scsh = (float*)((char*)wsu + SCSH_OFF);
      scsh[(e * C_ + tid) * 2 + 0] = sc;
      scsh[(e * C_ + tid) * 2 + 1] = bt - mn * sc;
    }
    return;
  }

  const int b  = bid / HP_;
  const int hp = bid % HP_;
  unsigned short* xrow = wsu + ((size_t)b * HP_ + hp) * WP_ * C_;

  if (hp == 0 || hp == HP_ - 1) {           // zero pad rows
    u16x8 z = (u16x8)0;
    for (int c = tid; c < WP_ * C_ / 8; c += 256) *(u16x8*)(xrow + c * 8) = z;
    return;
  }

  __shared__ float tile[C_ * W_];           // 16 KB
  const int h = hp - 1;
#pragma unroll
  for (int p = 0; p < 4; ++p) {
    int n  = p * 1024 + tid * 4;
    int c  = n >> 7;
    int px = n & 127;
    *(f32x4*)(tile + n) =
        *(const f32x4*)(x + (((size_t)b * C_ + c) * H_ + h) * W_ + px);
  }
  __syncthreads();

  const int px = tid >> 1;
  const int c0 = (tid & 1) * 16;
  u16x8 o0, o1;
#pragma unroll
  for (int j = 0; j < 8; ++j) o0[j] = f2bf(tile[(c0 + j) * W_ + px]);
#pragma unroll
  for (int j = 0; j < 8; ++j) o1[j] = f2bf(tile[(c0 + 8 + j) * W_ + px]);
  unsigned short* dst = xrow + (px + 1) * C_ + c0;
  *(u16x8*)dst = o0;
  *(u16x8*)(dst + 8) = o1;

  if (tid < 4) {                            // zero pad cols 0 and 129
    int pxb = (tid >> 1) ? (WP_ - 1) : 0;
    int hf  = tid & 1;
    u16x8 z = (u16x8)0;
    unsigned short* d2 = xrow + pxb * C_ + hf * 16;
    *(u16x8*)d2 = z;
    *(u16x8*)(d2 + 8) = z;
  }
}

// ---------------- phase B: conv via MFMA, DMA staging ----------------
__global__ __launch_bounds__(256, 2)
void conv_kernel(const unsigned short* __restrict__ xpad,
                 const unsigned short* __restrict__ aw_all,
                 const float* __restrict__ scsh_all,
                 const float* __restrict__ weights,
                 const int* __restrict__ indices,
                 float* __restrict__ out) {
  __shared__ __align__(16) unsigned char lds[LDS_TOT];
  const int tid  = threadIdx.x;
  const int lane = tid & 63;
  const int wid  = tid >> 6;

  // XCD swizzle: all 16 blocks of a sample land on one XCD (bid%8 assumption).
  const int bid = blockIdx.x;
  const int xcd = bid & 7;
  const int ii  = bid >> 3;
  const int b   = (ii >> 4) * 8 + xcd;      // bijective over (b, tg)
  const int tg  = ii & 15;                  // 4-tile group 0..15

  const int   e0  = indices[b * K_ + 0];
  const int   e1  = indices[b * K_ + 1];
  const float wk0 = weights[b * K_ + 0];
  const float wk1 = weights[b * K_ + 1];
  const bool  dup = (e0 == e1);
  const float wka = dup ? (wk0 + wk1) : wk0;

  // ---- stage A panels (1 or 2 experts) via global_load_lds ----
  {
    const int nA = (dup ? 1 : 2) * 1184;    // 16B chunks
    for (int base = wid * 64; base < nA; base += 256) {
      int c = base + lane;
      int e = (c < 1184) ? e0 : e1;
      int r = (c < 1184) ? c : c - 1184;
      const unsigned short* src = aw_all + (size_t)e * (A_LDS_B / 2) + r * 8;
      if (c < nA) gload16(src, lds + LDS_AW + base * 16);
    }
  }
  // ---- stage BN scale/shift ----
  if (tid < 2 * C_) {
    int s  = tid >> 5;
    int co = tid & 31;
    int e  = s ? e1 : e0;
    float* d = (float*)(lds + LDS_SCSH) + (s * C_ + co) * 2;
    d[0] = scsh_all[(e * C_ + co) * 2 + 0];
    d[1] = scsh_all[(e * C_ + co) * 2 + 1];
  }

  const int lx = lane & 15;
  const int sl = lane >> 4;

  auto stage_input = [&](int tt, int bufoff) {
    int tile = tg * 4 + tt;
    int th0 = (tile >> 3) * TH;
    int tw0 = (tile & 7) * TW;
    for (int base = wid * 64; base < NCHUNK; base += 256) {
      int q    = base + lane;
      int px   = q >> 2;
      int slot = q & 3;
      int cb   = slot ^ ((px >> 1) & 3);    // source pre-swizzle
      int hy   = px / HALO;
      int hx   = px - hy * HALO;
      const unsigned short* src =
          xpad + ((size_t)(b * HP_ + th0 + hy) * WP_ + (tw0 + hx)) * C_ + cb * 8;
      if (q < NCHUNK) gload16(src, lds + bufoff + base * 16);
    }
  };

  stage_input(0, LDS_BUF0);
  __syncthreads();                          // drains vmcnt+lgkmcnt

  int curoff = LDS_BUF0;
#pragma unroll 1
  for (int tt = 0; tt < 4; ++tt) {
    int nxtoff = (curoff == LDS_BUF0) ? LDS_BUF1 : LDS_BUF0;
    if (tt < 3) stage_input(tt + 1, nxtoff);   // async, in flight over compute

    f32x4 acc[2][2][4];
#pragma unroll
    for (int s = 0; s < 2; ++s)
#pragma unroll
      for (int m = 0; m < 2; ++m)
#pragma unroll
        for (int j = 0; j < 4; ++j) acc[s][m][j] = (f32x4){0.f, 0.f, 0.f, 0.f};

    const unsigned char* bufp = lds + curoff;
    int dy = 0, dx = 0;
#pragma unroll 1
    for (int o = 0; o < 9; ++o) {
      bf16x8 bf[4];
#pragma unroll
      for (int j = 0; j < 4; ++j) {
        int hp2  = (4 * wid + j + dy) * HALO + (lx + dx);
        int slot = sl ^ ((hp2 >> 1) & 3);
        bf[j] = *(const bf16x8*)(bufp + (hp2 * 4 + slot) * 16);
      }
      bf16x8 af0[2], af1[2];
#pragma unroll
      for (int m = 0; m < 2; ++m) {
        int ro = (m * 16 + lx) * AROW_B + o * 64 + sl * 16;
        af0[m] = *(const bf16x8*)(lds + LDS_AW + ro);
      }
      if (!dup) {
#pragma unroll
        for (int m = 0; m < 2; ++m) {
          int ro = (m * 16 + lx) * AROW_B + o * 64 + sl * 16;
          af1[m] = *(const bf16x8*)(lds + LDS_AW + A_LDS_B + ro);
        }
      }
#pragma unroll
      for (int m = 0; m < 2; ++m)
#pragma unroll
        for (int j = 0; j < 4; ++j)
          acc[0][m][j] = __builtin_amdgcn_mfma_f32_16x16x32_bf16(af0[m], bf[j], acc[0][m][j], 0, 0, 0);
      if (!dup) {
#pragma unroll
        for (int m = 0; m < 2; ++m)
#pragma unroll
          for (int j = 0; j < 4; ++j)
            acc[1][m][j] = __builtin_amdgcn_mfma_f32_16x16x32_bf16(af1[m], bf[j], acc[1][m][j], 0, 0, 0);
      }
      if (++dx == 3) { dx = 0; ++dy; }
    }

    // ---- epilogue: BN + SiLU + routed combine + store ----
    float res[2][4][4];
#pragma unroll
    for (int m = 0; m < 2; ++m)
#pragma unroll
      for (int j = 0; j < 4; ++j)
#pragma unroll
        for (int r = 0; r < 4; ++r) res[m][j][r] = 0.f;

    const float* scshl = (const float*)(lds + LDS_SCSH);
#pragma unroll
    for (int s = 0; s < 2; ++s) {
      if (s == 1 && dup) break;
      float wk = s ? wk1 : wka;
#pragma unroll
      for (int m = 0; m < 2; ++m)
#pragma unroll
        for (int r = 0; r < 4; ++r) {
          int co = m * 16 + sl * 4 + r;
          float sc = scshl[(s * C_ + co) * 2 + 0];
          float sh = scshl[(s * C_ + co) * 2 + 1];
#pragma unroll
          for (int j = 0; j < 4; ++j) {
            float y = acc[s][m][j][r] * sc + sh;
            float sig = 1.f / (1.f + __expf(-y));
            res[m][j][r] += wk * y * sig;
          }
        }
    }

    int tile = tg * 4 + tt;
    int th0 = (tile >> 3) * TH;
    int tw0 = (tile & 7) * TW;
#pragma unroll
    for (int m = 0; m < 2; ++m)
#pragma unroll
      for (int r = 0; r < 4; ++r) {
        int co = m * 16 + sl * 4 + r;
        float* ob = out + ((size_t)b * C_ + co) * HW_ + (size_t)th0 * W_ + tw0 + lx;
#pragma unroll
        for (int j = 0; j < 4; ++j)
          ob[(size_t)(4 * wid + j) * W_] = res[m][j][r];
      }

    __syncthreads();                        // next-tile stage complete; buf free
    curoff = nxtoff;
  }
}

// ---------------- fallback (R2 single kernel) if ws too small ----------------
#define FHALO 18
#define FNPX (FHALO * FHALO)
#define FPX_B 64
#define FIN_LDS_B (FNPX * FPX_B)
#define FSC_OFF (FIN_LDS_B + 2 * A_LDS_B)
#define FLDS_TOTAL (FSC_OFF + 2 * C_ * 8)

__global__ __launch_bounds__(256, 2)
void moe_fallback_kernel(const float* __restrict__ x,
                         const float* __restrict__ weights,
                         const int* __restrict__ indices,
                         const float* __restrict__ Wc,
                         const float* __restrict__ gamma,
                         const float* __restrict__ beta,
                         const float* __restrict__ mean,
                         const float* __restrict__ var,
                         float* __restrict__ out) {
  __shared__ __align__(16) unsigned char lds[FLDS_TOTAL];
  unsigned char* in_t = lds;
  unsigned char* aw0  = lds + FIN_LDS_B;
  unsigned char* aw1  = lds + FIN_LDS_B + A_LDS_B;
  float*         scsh = (float*)(lds + FSC_OFF);

  const int tid = threadIdx.x;
  const int tiles_per_row = W_ / TW;
  const int tiles_per_img = (H_ / TH) * tiles_per_row;
  const int b    = blockIdx.x / tiles_per_img;
  const int tile = blockIdx.x % tiles_per_img;
  const int th0  = (tile / tiles_per_row) * TH;
  const int tw0  = (tile % tiles_per_row) * TW;

  const int   e0  = indices[b * K_ + 0];
  const int   e1  = indices[b * K_ + 1];
  const float wk0 = weights[b * K_ + 0];
  const float wk1 = weights[b * K_ + 1];
  const bool  dup = (e0 == e1);
  const float wka = dup ? (wk0 + wk1) : wk0;

  const float* xb = x + (size_t)b * C_ * HW_;
  for (int i = tid; i < FNPX * 4; i += 256) {
    int px = i % FNPX;
    int cb = i / FNPX;
    int hy = px / FHALO, hx = px % FHALO;
    int gh = th0 + hy - 1, gw = tw0 + hx - 1;
    u16x8 pk = (u16x8)0;
    if (gh >= 0 && gh < H_ && gw >= 0 && gw < W_) {
      const float* src = xb + (size_t)(cb * 8) * HW_ + (size_t)gh * W_ + gw;
#pragma unroll
      for (int j = 0; j < 8; ++j) pk[j] = f2bf(src[(size_t)j * HW_]);
    }
    int slot = cb ^ (px & 3);
    *(u16x8*)(in_t + px * FPX_B + slot * 16) = pk;
  }
  {
    int co  = tid >> 3;
    int ci4 = (tid & 7) * 4;
#pragma unroll
    for (int s = 0; s < 2; ++s) {
      int e = s ? e1 : e0;
      const float* wp = Wc + (size_t)e * C_ * C_ * 9 + (size_t)co * C_ * 9 + (size_t)ci4 * 9;
      float wv[36];
#pragma unroll
      for (int j = 0; j < 36; ++j) wv[j] = wp[j];
      unsigned char* arow = (s ? aw1 : aw0) + co * AROW_B + ci4 * 2;
#pragma unroll
      for (int o = 0; o < 9; ++o) {
        u16x4 pk;
#pragma unroll
        for (int q = 0; q < 4; ++q) pk[q] = f2bf(wv[q * 9 + o]);
        *(u16x4*)(arow + o * 64) = pk;
      }
    }
  }
  if (tid < 64) {
    int s  = tid >> 5;
    int co = tid & 31;
    int e  = s ? e1 : e0;
    float g  = gamma[e * C_ + co];
    float bt = beta[e * C_ + co];
    float mn = mean[e * C_ + co];
    float vr = var[e * C_ + co];
    float sc = g * rsqrtf(vr + EPS_);
    scsh[(s * C_ + co) * 2 + 0] = sc;
    scsh[(s * C_ + co) * 2 + 1] = bt - mn * sc;
  }
  __syncthreads();

  const int lane = tid & 63;
  const int w    = tid >> 6;
  const int lx   = lane & 15;
  const int sl   = lane >> 4;

  f32x4 acc[2][2][4];
#pragma unroll
  for (int s = 0; s < 2; ++s)
#pragma unroll
    for (int m = 0; m < 2; ++m)
#pragma unroll
      for (int j = 0; j < 4; ++j) acc[s][m][j] = (f32x4){0.f, 0.f, 0.f, 0.f};

  int dy = 0, dx = 0;
#pragma unroll 1
  for (int o = 0; o < 9; ++o) {
    bf16x8 bf[4];
#pragma unroll
    for (int j = 0; j < 4; ++j) {
      int hp   = (4 * w + j + dy) * FHALO + (lx + dx);
      int slot = sl ^ (hp & 3);
      bf[j] = *(const bf16x8*)(in_t + hp * FPX_B + slot * 16);
    }
    bf16x8 af0[2], af1[2];
#pragma unroll
    for (int m = 0; m < 2; ++m) {
      int ro = (m * 16 + lx) * AROW_B + o * 64 + sl * 16;
      af0[m] = *(const bf16x8*)(aw0 + ro);
      af1[m] = *(const bf16x8*)(aw1 + ro);
    }
#pragma unroll
    for (int m = 0; m < 2; ++m)
#pragma unroll
      for (int j = 0; j < 4; ++j)
        acc[0][m][j] = __builtin_amdgcn_mfma_f32_16x16x32_bf16(af0[m], bf[j], acc[0][m][j], 0, 0, 0);
    if (!dup) {
#pragma unroll
      for (int m = 0; m < 2; ++m)
#pragma unroll
        for (int j = 0; j < 4; ++j)
          acc[1][m][j] = __builtin_amdgcn_mfma_f32_16x16x32_bf16(af1[m], bf[j], acc[1][m][j], 0, 0, 0);
    }
    if (++dx == 3) { dx = 0; ++dy; }
  }

  float res[2][4][4];
#pragma unroll
  for (int m = 0; m < 2; ++m)
#pragma unroll
    for (int j = 0; j < 4; ++j)
#pragma unroll
      for (int r = 0; r < 4; ++r) res[m][j][r] = 0.f;

#pragma unroll
  for (int s = 0; s < 2; ++s) {
    if (s == 1 && dup) break;
    float wk = s ? wk1 : wka;
#pragma unroll
    for (int m = 0; m < 2; ++m)
#pragma unroll
      for (int r = 0; r < 4; ++r) {
        int co = m * 16 + sl * 4 + r;
        float sc = scsh[(s * C_ + co) * 2 + 0];
        float sh = scsh[(s * C_ + co) * 2 + 1];
#pragma unroll
        for (int j = 0; j < 4; ++j) {
          float y = acc[s][m][j][r] * sc + sh;
          float sig = 1.f / (1.f + __expf(-y));
          res[m][j][r] += wk * y * sig;
        }
      }
  }
#pragma unroll
  for (int m = 0; m < 2; ++m)
#pragma unroll
    for (int r = 0; r < 4; ++r) {
      int co = m * 16 + sl * 4 + r;
      float* ob = out + ((size_t)b * C_ + co) * HW_ + (size_t)th0 * W_ + tw0 + lx;
#pragma unroll
      for (int j = 0; j < 4; ++j)
        ob[(size_t)(4 * w + j) * W_] = res[m][j][r];
    }
}

extern "C" void kernel_launch(void* const* d_in, const int* in_sizes, int n_in,
                              void* d_out, int out_size, void* d_ws, size_t ws_size,
                              hipStream_t stream) {
  const float* x       = (const float*)d_in[0];
  const float* weights = (const float*)d_in[1];
  const int*   indices = (const int*)d_in[2];
  const float* Wc      = (const float*)d_in[3];
  const float* gamma   = (const float*)d_in[4];
  const float* beta    = (const float*)d_in[5];
  const float* mean    = (const float*)d_in[6];
  const float* var     = (const float*)d_in[7];
  float* out = (float*)d_out;

  if (d_ws != nullptr && ws_size >= WS_NEEDED) {
    unsigned short* wsu = (unsigned short*)d_ws;
    const unsigned short* aw_all  = (const unsigned short*)((char*)d_ws + AW_OFF);
    const float*          scsh_all = (const float*)((char*)d_ws + SCSH_OFF);
    prep_kernel<<<B_ * HP_ + E_, 256, 0, stream>>>(x, Wc, gamma, beta, mean, var, wsu);
    conv_kernel<<<B_ * 16, 256, 0, stream>>>(wsu, aw_all, scsh_all, weights, indices, out);
  } else {
    moe_fallback_kernel<<<B_ * 64, 256, 0, stream>>>(
        x, weights, indices, Wc, gamma, beta, mean, var, out);
  }
}